// Round 11
// baseline (74.152 us; speedup 1.0000x reference)
//
#include <hip/hip_runtime.h>
#include <stdint.h>

#define NROW 16384
#define DDIM 128
#define ROWB 256            // bytes per row of bf16 z

constexpr int NB    = 64;               // cols per j-tile
constexpr int NJT   = NROW / NB;        // 256 j-tiles
constexpr int CHUNK = 16;               // max j-tiles per block
// 64-row strips: strip I in [0,256), tiles j>=I, count t=256-I.
// blocks = sum_t ceil(t/16) for t=1..256 = 2176
constexpr int NBLK  = 2176;

typedef __bf16 bf16x8 __attribute__((ext_vector_type(8)));
typedef float  f32x4  __attribute__((ext_vector_type(4)));
typedef int    i32x4  __attribute__((ext_vector_type(4)));

typedef const uint32_t __attribute__((address_space(1)))* gptr_t;
typedef uint32_t __attribute__((address_space(3)))*       lptr_t;

__device__ __forceinline__ unsigned short f2bf(float x) {
  union { float f; uint32_t u; } c; c.f = x;
  uint32_t u = c.u + 0x7fffu + ((c.u >> 16) & 1u);   // RNE
  return (unsigned short)(u >> 16);
}

// U(t) = blocks in the last t strips = sum_{m=1..t} ceil(m/16)
__device__ __forceinline__ int Ufun(int t) {
  const int q = t >> 4, r = t & 15;
  return 8 * q * (q + 1) + r * (q + 1);
}

// fp32 -> bf16 with the scale folded in: (1/T) * sqrt(log2(e)),
// so the MFMA accumulator equals a*log2(e), ready for v_exp_f32 (exp2).
__global__ __launch_bounds__(256) void prep_kernel(const float* __restrict__ z,
                                                   unsigned short* __restrict__ zs,
                                                   float* __restrict__ s) {
  const float SC = 12.011224087864498f;  // 10 * sqrt(1.4426950408889634)
  int t = blockIdx.x * 256 + threadIdx.x;
  float4 v = reinterpret_cast<const float4*>(z)[t];
  ushort4 o;
  o.x = f2bf(v.x * SC); o.y = f2bf(v.y * SC);
  o.z = f2bf(v.z * SC); o.w = f2bf(v.w * SC);
  reinterpret_cast<ushort4*>(zs)[t] = o;
  if (t < NROW) s[t] = 0.0f;             // rowsum accumulator (ws is poisoned)
}

// Round-11: BARRIER-FREE main loop. 10 rounds showed wall time = work floor /
// stall-fill, capped by the 2-barrier-per-tile lockstep (r10: conflicts->0
// moved dur only 4%). Fix the structure: wave w consumes ONLY cols
// [16w,16w+16) of each 64-col j-tile and stages that slice ITSELF into a
// wave-private LDS double-buffer (same total staged bytes/instrs as shared
// staging) -> sync is the wave's own counted vmcnt; zero s_barrier in loop.
//   block = 64-row strip x CHUNK tiles; wave = all 64 rows x 16-col slice.
//   rowsums: per-wave 16-col partials, one LDS combine after the loop.
//   colsums: wave-private cols -> private csm slab, no atomics.
// Kept: symmetry (colsum=transposed rowsum; diagonal 64-square self-paired),
// nibble swizzle both-sides (r10: 0 conflicts), rolled loop (r3), no forced
// occupancy (r2), setprio around compute (r10).
__global__ __launch_bounds__(256, 2) void gemm_exp_kernel(const unsigned short* __restrict__ zs,
                                                          float* __restrict__ s) {
  // [4 waves][2 bufs][4 KB slice] + csm[4][256] + rsum[4][64] = 37.9 KB
  __shared__ __align__(16) char smem[4 * 8192 + 4 * 256 * 4 + 4 * 64 * 4];
  float* csm  = (float*)(smem + 32768);          // [wave][CHUNK*16 cols]
  float* rsum = (float*)(smem + 32768 + 4096);   // [wave][64 rows]
  const int tid  = threadIdx.x;
  const int lane = tid & 63;
  const int wid  = tid >> 6;

  // blockIdx.x -> (strip I, chunk c): smallest t with U(t) >= NBLK - bid.
  int I, c;
  {
    const int bid = blockIdx.x;
    const int m = NBLK - bid;                    // 1..NBLK
    int t = (int)sqrtf(32.0f * (float)m);
    if (t > 256) t = 256;
    if (t < 1) t = 1;
    while (Ufun(t) < m) ++t;
    while (t > 1 && Ufun(t - 1) >= m) --t;
    I = 256 - t;
    c = bid - (NBLK - Ufun(t));
  }
  const int tI     = 256 - I;                    // j-tiles in this strip
  const int jt0    = I + CHUNK * c;              // first global j-tile
  const int JT_blk = min(CHUNK, tI - CHUNK * c); // tiles this block runs

  const int rowBase = I * 64;                    // strip rows (all waves)
  const char* zb = (const char*)zs;
  const int kb = (lane >> 4) << 4;               // 16B chunk within K row
  char* wbuf = smem + wid * 8192;                // wave-private double buffer

  // Stage wave-private 16-col slice of j-tile (jt0+k): 16 zs-rows starting at
  // (jt0+k)*64 + wid*16. Linear LDS dest + inverse-swizzled source (rule #21).
#define STAGE_B(k)                                                               \
  {                                                                             \
    _Pragma("unroll")                                                           \
    for (int i_ = 0; i_ < 4; ++i_) {                                            \
      const int destByte_ = i_ * 1024 + lane * 16;                              \
      const int r_  = destByte_ >> 8;            /* slice row 0..15 */          \
      const int cb_ = destByte_ & 0xF0;                                         \
      const int srcByte_ = ((jt0 + (k)) * NB + wid * 16 + r_) * ROWB            \
                           + (cb_ ^ (r_ << 4));                                 \
      __builtin_amdgcn_global_load_lds((gptr_t)(zb + srcByte_),                 \
          (lptr_t)(wbuf + ((k) & 1) * 4096 + destByte_), 16, 0, 0);             \
    }                                                                           \
  }

  STAGE_B(0);

  // A fragments: all 64 strip rows, K=128. row=lane&15, k=(lane>>4)*8+e.
  // (Issued after STAGE(0); the loop's first vmcnt(4) drains these too.)
  bf16x8 afrag[4][4];   // [mf][ks]
  {
    const int r0 = rowBase + (lane & 15);
#pragma unroll
    for (int mf = 0; mf < 4; ++mf)
#pragma unroll
      for (int ks = 0; ks < 4; ++ks) {
        i32x4 raw = *reinterpret_cast<const i32x4*>(
            zb + (size_t)(r0 + mf * 16) * ROWB + ks * 64 + kb);
        afrag[mf][ks] = __builtin_bit_cast(bf16x8, raw);
      }
  }

  f32x4 rs[4];      // rowsum partials (16-col slice), [mf] -> 4 rows each
  float csl = 0.f;  // colsum partial for col lane&15, this tile
#pragma unroll
  for (int mf = 0; mf < 4; ++mf) rs[mf] = (f32x4){0.f, 0.f, 0.f, 0.f};

#pragma unroll 1    // KEEP ROLLED (r3: unrolling pipelines iters -> spills)
  for (int k = 0; k < JT_blk; ++k) {
    if (k + 1 < JT_blk) {
      STAGE_B(k + 1);
      // own tile-k slice landed (4 newest in flight = tile k+1)
      asm volatile("s_waitcnt vmcnt(4)" ::: "memory");
    } else {
      asm volatile("s_waitcnt vmcnt(0)" ::: "memory");
    }
    // NO BARRIER: buffer is wave-private; wave paces itself.

    f32x4 acc[4];
#pragma unroll
    for (int mf = 0; mf < 4; ++mf) acc[mf] = (f32x4){0.f, 0.f, 0.f, 0.f};

    __builtin_amdgcn_s_setprio(1);
    const char* bufp = wbuf + (k & 1) * 4096;
#pragma unroll
    for (int ks = 0; ks < 4; ++ks) {
      const int r   = lane & 15;
      const int kk  = ks * 64 + kb;
      const int off = r * 256 + (kk ^ (r << 4));
      i32x4 raw = *reinterpret_cast<const i32x4*>(bufp + off);
      bf16x8 bfrag = __builtin_bit_cast(bf16x8, raw);
#pragma unroll
      for (int mf = 0; mf < 4; ++mf)
        acc[mf] = __builtin_amdgcn_mfma_f32_16x16x32_bf16(
            afrag[mf][ks], bfrag, acc[mf], 0, 0, 0);
    }
    __builtin_amdgcn_s_setprio(0);

    // acc = a*log2(e) -> exp(a) = exp2(acc). C/D layout: col=lane&15,
    // row = mf*16 + (lane>>4)*4 + r.
#pragma unroll
    for (int mf = 0; mf < 4; ++mf) {
      f32x4 a4 = acc[mf];
      f32x4 ev;
      ev[0] = __builtin_amdgcn_exp2f(a4[0]);
      ev[1] = __builtin_amdgcn_exp2f(a4[1]);
      ev[2] = __builtin_amdgcn_exp2f(a4[2]);
      ev[3] = __builtin_amdgcn_exp2f(a4[3]);
      rs[mf] += ev;
      csl += (ev[0] + ev[1]) + (ev[2] + ev[3]);
    }

    // Colsum flush: sum the 4 lane-hi groups (rows 0..63), park in private csm.
    {
      float v = csl;
      v += __shfl_xor(v, 16);
      v += __shfl_xor(v, 32);
      if (lane < 16) csm[wid * 256 + k * 16 + lane] = v;
      csl = 0.0f;
    }
  }
#undef STAGE_B

  // Rowsum partials (16 cols each) -> LDS, combine across waves once.
#pragma unroll
  for (int mf = 0; mf < 4; ++mf)
#pragma unroll
    for (int r = 0; r < 4; ++r) {
      float v = rs[mf][r];
      v += __shfl_xor(v, 1);
      v += __shfl_xor(v, 2);
      v += __shfl_xor(v, 4);
      v += __shfl_xor(v, 8);
      if ((lane & 15) == 0)
        rsum[wid * 64 + mf * 16 + ((lane >> 4) << 2) + r] = v;
    }
  __syncthreads();   // publish rsum + csm across waves

  // Rowsums: one atomic per strip row.
  if (tid < 64) {
    float v = rsum[tid] + rsum[64 + tid] + rsum[128 + tid] + rsum[192 + tid];
    atomicAdd(&s[rowBase + tid], v);
  }

  // Colsums: one atomic per column; skip the diagonal tile (j == I), whose
  // 64x64 square is its own transpose (rowsums there already cover it).
  {
    const int ncol = JT_blk * NB;
    for (int cc = tid; cc < ncol; cc += 256) {
      const int kt = cc >> 6;                     // tile index in chunk
      if (jt0 + kt != I) {
        const float v = csm[((cc >> 4) & 3) * 256 + kt * 16 + (cc & 15)];
        atomicAdd(&s[jt0 * NB + cc], v);
      }
    }
  }
}

__global__ __launch_bounds__(1024) void reduce_kernel(const float* __restrict__ s,
                                                      float* __restrict__ out) {
  const int tid = threadIdx.x;
  float acc = 0.0f;
  for (int i = tid; i < NROW; i += 1024) acc += __log2f(s[i]);
#pragma unroll
  for (int m = 32; m >= 1; m >>= 1) acc += __shfl_xor(acc, m);
  __shared__ float wsum[16];
  if ((tid & 63) == 0) wsum[tid >> 6] = acc;
  __syncthreads();
  if (tid == 0) {
    float tot = 0.0f;
#pragma unroll
    for (int w = 0; w < 16; ++w) tot += wsum[w];
    // mean(-log(sum/N)) = log N - (ln2/N) * sum(log2 s_i)
    out[0] = logf((float)NROW) - 0.6931471805599453f * tot / (float)NROW;
  }
}

extern "C" void kernel_launch(void* const* d_in, const int* in_sizes, int n_in,
                              void* d_out, int out_size, void* d_ws, size_t ws_size,
                              hipStream_t stream) {
  const float* z = (const float*)d_in[0];
  unsigned short* zs = (unsigned short*)d_ws;                       // 4 MB bf16
  float* s = (float*)((char*)d_ws + (size_t)NROW * DDIM * 2);       // 64 KB rowsums
  float* out = (float*)d_out;

  prep_kernel<<<dim3(NROW * DDIM / 4 / 256), dim3(256), 0, stream>>>(z, zs, s);
  gemm_exp_kernel<<<dim3(NBLK), dim3(256), 0, stream>>>(zs, s);
  reduce_kernel<<<dim3(1), dim3(1024), 0, stream>>>(s, out);
}

// Round 12
// 64.901 us; speedup vs baseline: 1.1425x; 1.1425x over previous
//
#include <hip/hip_runtime.h>
#include <stdint.h>

#define NROW 16384
#define DDIM 128
#define ROWB 256            // bytes per row of bf16 z

constexpr int NB     = 64;              // cols per j-tile
constexpr int NJT    = NROW / NB;       // 256 j-tiles across the matrix
constexpr int CHUNK  = 8;               // max j-tiles per block
// 128-row strips; strip I has ceil((256-2I)/8) blocks; total = 2112
constexpr int NBLK   = 2112;

typedef __bf16 bf16x8 __attribute__((ext_vector_type(8)));
typedef float  f32x4  __attribute__((ext_vector_type(4)));
typedef int    i32x4  __attribute__((ext_vector_type(4)));

typedef const uint32_t __attribute__((address_space(1)))* gptr_t;
typedef uint32_t __attribute__((address_space(3)))*       lptr_t;

__device__ __forceinline__ unsigned short f2bf(float x) {
  union { float f; uint32_t u; } c; c.f = x;
  uint32_t u = c.u + 0x7fffu + ((c.u >> 16) & 1u);   // RNE
  return (unsigned short)(u >> 16);
}

// S(k) = sum_{x=1..k} ceil(x/4)  (blocks in the last k strips)
__device__ __forceinline__ int Sfun(int k) {
  const int q = k >> 2, r = k & 3;
  return 2 * q * (q + 1) + r * (q + 1);
}

// fp32 -> bf16 with the scale folded in: (1/T) * sqrt(log2(e)),
// so the MFMA accumulator equals a*log2(e), ready for v_exp_f32 (exp2).
__global__ __launch_bounds__(256) void prep_kernel(const float* __restrict__ z,
                                                   unsigned short* __restrict__ zs,
                                                   float* __restrict__ s,
                                                   float* __restrict__ out) {
  const float SC = 12.011224087864498f;  // 10 * sqrt(1.4426950408889634)
  int t = blockIdx.x * 256 + threadIdx.x;
  float4 v = reinterpret_cast<const float4*>(z)[t];
  ushort4 o;
  o.x = f2bf(v.x * SC); o.y = f2bf(v.y * SC);
  o.z = f2bf(v.z * SC); o.w = f2bf(v.w * SC);
  reinterpret_cast<ushort4*>(zs)[t] = o;
  if (t < NROW) s[t] = 0.0f;             // rowsum accumulator (ws is poisoned)
  if (t == 0) out[0] = 9.704060527839234f;   // log(16384); reduce adds to it
}

// Symmetry via 128-row strips (r10 skeleton, best: 57.9us gemm). Round-12 is
// a VALU-elimination pass on the identical schedule: r10's counters showed
// VALU-busy ~856cy/wave-tile vs ~220cy algorithmic (exp2+adds) -- the rest
// was per-tile ds_read address recompute (16x XOR+mul+add), 32 acc-zero
// moves, and staging address recompute. Fixes:
//  (1) hand pair-unrolled loop with STATIC buf0/buf1 paths: LDS read
//      addresses precomputed once (rq[ks]); nf*4096 and parity 16384 fold
//      into the ds_read immediate. Outer loop stays rolled (r3 lesson).
//  (2) staging addresses strength-reduced: sOff[4] += 16KB per tile.
//  (3) zero-C MFMA on ks=0 (no per-tile accumulator zeroing).
// Kept: nibble swizzle both-sides (r10: conflicts->0), depth-1 counted
// vmcnt(4) dbuf (r7/r9: worth ~18us), 2 barriers/tile, setprio, CHUNK=8.
__global__ __launch_bounds__(256, 2) void gemm_exp_kernel(const unsigned short* __restrict__ zs,
                                                          float* __restrict__ s) {
  __shared__ __align__(16) char smem[2 * NB * ROWB + 4 * CHUNK * 64 * 4]; // 32K dbuf + 8K csm
  float* csm = (float*)(smem + 2 * NB * ROWB);   // [4 waves][CHUNK*64 cols]
  const int tid  = threadIdx.x;
  const int lane = tid & 63;
  const int wid  = tid >> 6;

  // blockIdx.x -> (strip I, chunk c): smallest k with S(k) >= NBLK - bid.
  int I, c;
  {
    const int bid = blockIdx.x;
    const int m = NBLK - bid;
    int k = (int)sqrtf(8.0f * (float)m);
    if (k > 128) k = 128;
    if (k < 1) k = 1;
    while (Sfun(k) < m) ++k;
    while (k > 1 && Sfun(k - 1) >= m) --k;
    I = 128 - k;
    c = bid - (NBLK - Sfun(k));
  }
  const int mI     = NJT - 2 * I;                // j-tiles in this strip
  const int jt0    = 2 * I + CHUNK * c;          // first global j-tile
  const int JT_blk = min(CHUNK, mI - CHUNK * c); // tiles this block runs

  const int rowBase = I * 128 + wid * 32;        // this wave's 32 rows
  const char* zb = (const char*)zs;
  const int kb = (lane >> 4) << 4;               // 16B chunk within K row

  // ---- precomputed addresses (hoisted out of the loop entirely) ----
  // LDS read bases: read byte = r*256 + ((ks*64+kb) ^ (r<<4)) + nf*4096 (+P)
  const char* rq[4];
  {
    const int r = lane & 15;
#pragma unroll
    for (int ks = 0; ks < 4; ++ks)
      rq[ks] = smem + r * 256 + ((ks * 64 + kb) ^ (r << 4));
  }
  // staging: linear LDS dest base + inverse-swizzled global src offsets,
  // advanced by one tile (16 KB) per STAGE.
  const int dBase = wid * 4096 + lane * 16;
  int sOff[4];
#pragma unroll
  for (int i_ = 0; i_ < 4; ++i_) {
    const int db  = dBase + i_ * 1024;
    const int r_  = db >> 8;
    const int cb_ = db & 0xF0;
    sOff[i_] = (jt0 * NB + r_) * ROWB + (cb_ ^ ((r_ & 15) << 4));
  }

#define STAGE(P)                                                               \
  {                                                                            \
    _Pragma("unroll")                                                          \
    for (int i_ = 0; i_ < 4; ++i_) {                                           \
      __builtin_amdgcn_global_load_lds((gptr_t)(zb + sOff[i_]),                \
          (lptr_t)(smem + (P) + dBase + i_ * 1024), 16, 0, 0);                 \
      sOff[i_] += NB * ROWB;                                                   \
    }                                                                          \
  }

  STAGE(0);   // tile 0 -> buf0

  // A fragments: 16x16x32 A layout row=lane&15, k=(lane>>4)*8+e -> 16B/lane
  bf16x8 afrag[2][4];   // [mf][ks]
  {
    const int r0 = rowBase + (lane & 15);
#pragma unroll
    for (int mf = 0; mf < 2; ++mf)
#pragma unroll
      for (int ks = 0; ks < 4; ++ks) {
        i32x4 raw = *reinterpret_cast<const i32x4*>(
            zb + (size_t)(r0 + mf * 16) * ROWB + ks * 64 + kb);
        afrag[mf][ks] = __builtin_bit_cast(bf16x8, raw);
      }
  }

  f32x4 rsv[2];     // rowsum accumulators
  float cs[4];      // colsum accumulators [nf], flushed to LDS each tile
  rsv[0] = (f32x4){0.f, 0.f, 0.f, 0.f};
  rsv[1] = (f32x4){0.f, 0.f, 0.f, 0.f};
#pragma unroll
  for (int nf = 0; nf < 4; ++nf) cs[nf] = 0.0f;
  const f32x4 kZ = {0.f, 0.f, 0.f, 0.f};   // zero-C operand for ks=0 MFMA

#define COMPUTE(P, kk)                                                         \
  {                                                                            \
    f32x4 acc[2][4];                                                           \
    __builtin_amdgcn_s_setprio(1);                                             \
    _Pragma("unroll")                                                          \
    for (int ks = 0; ks < 4; ++ks) {                                           \
      bf16x8 bfr[4];                                                           \
      _Pragma("unroll")                                                        \
      for (int nf = 0; nf < 4; ++nf)                                           \
        bfr[nf] = __builtin_bit_cast(bf16x8,                                   \
            *reinterpret_cast<const i32x4*>(rq[ks] + nf * 4096 + (P)));        \
      if (ks == 0) {                                                           \
        _Pragma("unroll")                                                      \
        for (int mf = 0; mf < 2; ++mf)                                         \
          _Pragma("unroll")                                                    \
          for (int nf = 0; nf < 4; ++nf)                                       \
            acc[mf][nf] = __builtin_amdgcn_mfma_f32_16x16x32_bf16(             \
                afrag[mf][0], bfr[nf], kZ, 0, 0, 0);                           \
      } else {                                                                 \
        _Pragma("unroll")                                                      \
        for (int mf = 0; mf < 2; ++mf)                                         \
          _Pragma("unroll")                                                    \
          for (int nf = 0; nf < 4; ++nf)                                       \
            acc[mf][nf] = __builtin_amdgcn_mfma_f32_16x16x32_bf16(             \
                afrag[mf][ks], bfr[nf], acc[mf][nf], 0, 0, 0);                 \
      }                                                                        \
    }                                                                          \
    __builtin_amdgcn_s_setprio(0);                                             \
    _Pragma("unroll")                                                          \
    for (int mf = 0; mf < 2; ++mf)                                             \
      _Pragma("unroll")                                                        \
      for (int nf = 0; nf < 4; ++nf) {                                         \
        f32x4 a4 = acc[mf][nf];                                                \
        f32x4 ev;                                                              \
        ev[0] = __builtin_amdgcn_exp2f(a4[0]);                                 \
        ev[1] = __builtin_amdgcn_exp2f(a4[1]);                                 \
        ev[2] = __builtin_amdgcn_exp2f(a4[2]);                                 \
        ev[3] = __builtin_amdgcn_exp2f(a4[3]);                                 \
        rsv[mf] += ev;                                                         \
        cs[nf] += (ev[0] + ev[1]) + (ev[2] + ev[3]);                           \
      }                                                                        \
    _Pragma("unroll")                                                          \
    for (int nf = 0; nf < 4; ++nf) {                                           \
      float v = cs[nf];                                                        \
      v += __shfl_xor(v, 16);                                                  \
      v += __shfl_xor(v, 32);                                                  \
      if (lane < 16) csm[wid * (CHUNK * 64) + (kk) * 64 + nf * 16 + lane] = v; \
      cs[nf] = 0.0f;                                                           \
    }                                                                          \
  }

  // Pair-unrolled main loop: tiles k (buf0, P=0) and k+1 (buf1, P=16384).
  // Same schedule as r10 (stage-next -> vmcnt(4) -> barrier -> compute ->
  // barrier), just with static parity so all addressing is loop-invariant.
  int k = 0;
#pragma unroll 1
  for (; k + 2 <= JT_blk; k += 2) {
    STAGE(16384);                                   // tile k+1 -> buf1
    asm volatile("s_waitcnt vmcnt(4)" ::: "memory"); // tile k landed
    __builtin_amdgcn_s_barrier();
    COMPUTE(0, k);
    __builtin_amdgcn_s_barrier();                    // buf0 free

    if (k + 2 < JT_blk) {
      STAGE(0);                                      // tile k+2 -> buf0
      asm volatile("s_waitcnt vmcnt(4)" ::: "memory");
    } else {
      asm volatile("s_waitcnt vmcnt(0)" ::: "memory");
    }
    __builtin_amdgcn_s_barrier();
    COMPUTE(16384, k + 1);
    __builtin_amdgcn_s_barrier();                    // buf1 free
  }
  if (k < JT_blk) {                                  // odd tail: tile k in buf0
    asm volatile("s_waitcnt vmcnt(0)" ::: "memory");
    __builtin_amdgcn_s_barrier();
    COMPUTE(0, k);
    __builtin_amdgcn_s_barrier();
  }
#undef STAGE
#undef COMPUTE

  // Rowsums: C/D layout col=lane&15, row=(lane>>4)*4+reg. Reduce the 16
  // column-lanes, one atomicAdd per row.
#pragma unroll
  for (int mf = 0; mf < 2; ++mf)
#pragma unroll
    for (int r = 0; r < 4; ++r) {
      float v = rsv[mf][r];
      v += __shfl_xor(v, 1);
      v += __shfl_xor(v, 2);
      v += __shfl_xor(v, 4);
      v += __shfl_xor(v, 8);
      if ((lane & 15) == 0) {
        const int row = rowBase + mf * 16 + ((lane >> 4) << 2) + r;
        atomicAdd(&s[row], v);
      }
    }

  // Colsums: combine the 4 per-wave slabs, one atomic per column. Skip
  // columns inside this strip's diagonal 128-square (computed fully there).
  __syncthreads();   // drain csm ds_writes across waves
  {
    const int colBase0 = jt0 * NB;
    const int diagEnd  = (I + 1) * 128;
    const int ncol     = JT_blk * NB;
#pragma unroll
    for (int k4 = 0; k4 < 2; ++k4) {
      const int idx = k4 * 256 + tid;
      if (idx < ncol) {
        const int col = colBase0 + idx;
        if (col >= diagEnd) {
          float sum = csm[idx] + csm[CHUNK * 64 + idx]
                    + csm[2 * CHUNK * 64 + idx] + csm[3 * CHUNK * 64 + idx];
          atomicAdd(&s[col], sum);
        }
      }
    }
  }
}

// 64 blocks x 256 threads, 1 row each; out[0] pre-set to log N by prep.
// Float-atomic ordering jitter ~1e-7 << 4.4e-2 threshold.
__global__ __launch_bounds__(256) void reduce_kernel(const float* __restrict__ s,
                                                     float* __restrict__ out) {
  const int tid  = threadIdx.x;
  const int lane = tid & 63;
  const int wid  = tid >> 6;
  float v = __log2f(s[blockIdx.x * 256 + tid]);
#pragma unroll
  for (int m = 32; m >= 1; m >>= 1) v += __shfl_xor(v, m);
  __shared__ float ws[4];
  if (lane == 0) ws[wid] = v;
  __syncthreads();
  if (tid == 0) {
    const float t = ws[0] + ws[1] + ws[2] + ws[3];
    // contribution: -(ln2/N) * sum(log2 s_i)
    atomicAdd(out, -4.2307473367321867e-5f * t);  // ln2/16384
  }
}

extern "C" void kernel_launch(void* const* d_in, const int* in_sizes, int n_in,
                              void* d_out, int out_size, void* d_ws, size_t ws_size,
                              hipStream_t stream) {
  const float* z = (const float*)d_in[0];
  unsigned short* zs = (unsigned short*)d_ws;                       // 4 MB bf16
  float* s = (float*)((char*)d_ws + (size_t)NROW * DDIM * 2);       // 64 KB rowsums
  float* out = (float*)d_out;

  prep_kernel<<<dim3(NROW * DDIM / 4 / 256), dim3(256), 0, stream>>>(z, zs, s, out);
  gemm_exp_kernel<<<dim3(NBLK), dim3(256), 0, stream>>>(zs, s);
  reduce_kernel<<<dim3(64), dim3(256), 0, stream>>>(s, out);
}